// Round 9
// baseline (93.399 us; speedup 1.0000x reference)
//
#include <hip/hip_runtime.h>

typedef __attribute__((ext_vector_type(8))) short bf16x8;
typedef __attribute__((ext_vector_type(4))) float f32x4;
typedef __attribute__((ext_vector_type(2))) float f32x2;
typedef __attribute__((ext_vector_type(4))) unsigned int u32x4;

#define XP_BYTES (2048 * 3364 * 2)   // padded x, bf16: 32*64 planes of 58x58
#define BSTG_OFF XP_BYTES            // Weff: 512 x 1024 bf16, n-major (1 MB)

static __device__ __forceinline__ unsigned short f2bf(float v) {
    unsigned int u = __builtin_bit_cast(unsigned int, v);
    u += 0x7fffu + ((u >> 16) & 1u);
    return (unsigned short)(u >> 16);
}

// ---------------------------------------------------------------------------
// Prep: (a) pad+convert x to bf16 58x58 planes; (b) fold Hadamard transforms
// into direct-conv weights, n-major: weff[n'*1024 + c*16 + b*4 + a].
// ---------------------------------------------------------------------------
__global__ __launch_bounds__(256) void prep(const float* __restrict__ x,
                                            const float* __restrict__ w,
                                            unsigned char* __restrict__ ws)
{
    int bid = blockIdx.x;
    if (bid < 2048) {
        const float* src = x + (size_t)bid * 3136;
        unsigned int* dst = (unsigned int*)ws + (size_t)bid * 1682;
        for (int s = threadIdx.x; s < 1682; s += 256) {
            int r = s / 29, p = s - r * 29;
            float v0 = 0.f, v1 = 0.f;
            if (r >= 1 && r <= 56) {
                const float* row = src + (r - 1) * 56;
                if (p >= 1)  v0 = row[2 * p - 1];
                if (p <= 27) v1 = row[2 * p];
            }
            dst[s] = (unsigned int)f2bf(v0) | ((unsigned int)f2bf(v1) << 16);
        }
        return;
    }
    int idx = (bid - 2048) * 256 + threadIdx.x;   // (o,c) pair
    if (idx >= 128 * 64) return;
    int o = idx >> 6, c = idx & 63;
    const bool v2 = (o >= 64);
    const float Hm[4][4]  = {{1,1,1,1},{1,-1,1,-1},{1,1,-1,-1},{1,-1,-1,1}};
    const float H2m[4][4] = {{1,-1,1,-1},{1,1,1,1},{1,1,-1,-1},{1,-1,-1,1}};

    float wv[4][4];
    #pragma unroll
    for (int i = 0; i < 4; ++i)
        #pragma unroll
        for (int j = 0; j < 4; ++j)
            wv[i][j] = w[((o * 64 + c) * 4 + i) * 4 + j];

    float FA[4][4], FB[4][4], G[2][4];
    #pragma unroll
    for (int a = 0; a < 4; ++a)
        #pragma unroll
        for (int i = 0; i < 4; ++i) {
            FA[a][i] = v2 ? H2m[a][i] : Hm[i][a];
            FB[a][i] = v2 ? H2m[a][i] : Hm[a][i];
        }
    #pragma unroll
    for (int p = 0; p < 2; ++p)
        #pragma unroll
        for (int i = 0; i < 4; ++i)
            G[p][i] = 0.25f * (v2 ? H2m[p + 1][i] : Hm[p + 1][i]);

    unsigned short* weff = (unsigned short*)(ws + BSTG_OFF);
    #pragma unroll
    for (int P = 0; P < 2; ++P)
    #pragma unroll
    for (int Q = 0; Q < 2; ++Q) {
        int nrow = o * 4 + P * 2 + Q;
        #pragma unroll
        for (int b = 0; b < 4; ++b)
        #pragma unroll
        for (int a = 0; a < 4; ++a) {
            float s = 0.f;
            #pragma unroll
            for (int i = 0; i < 4; ++i) {
                float sj = 0.f;
                #pragma unroll
                for (int j = 0; j < 4; ++j)
                    sj += FB[b][j] * G[Q][j] * wv[i][j];
                s += G[P][i] * FA[a][i] * sj;
            }
            weff[(size_t)nrow * 1024 + c * 16 + b * 4 + a] = f2bf(s);
        }
    }
}

// ---------------------------------------------------------------------------
// Main GEMM. M=25088 (196x128), N=512 (4x128), K=1024 (16 steps x 64).
// 256 thr = 4 waves (2m x 2n); wave = 64m x 64n, 32 MFMA(16x16x32)/step.
// A: coalesced gather -> regs -> XOR-swizzled LDS (barrier'd, lgkm only).
// B: direct global -> per-wave regs (no LDS, no barrier dependency).
// LDS 33.8KB -> 3 blocks/CU (12 waves): TLP hides L2 latency across blocks.
// Epilogue: per-wave LDS transpose -> contiguous float2 stores.
// ---------------------------------------------------------------------------
__global__ __launch_bounds__(256, 3) void conv_gemm(
    const unsigned short* __restrict__ xp,
    const unsigned short* __restrict__ weff,
    const float* __restrict__ bias,
    float* __restrict__ out)
{
    __shared__ __align__(16) unsigned char Abuf[2][16384];
    __shared__ int s_pbase[128];
    __shared__ int s_obase[128];

    const int tid  = threadIdx.x;
    const int lane = tid & 63;
    const int l15  = lane & 15;
    const int g    = lane >> 4;
    const int wv   = tid >> 6;
    const int wm   = wv >> 1, wn = wv & 1;
    const int bid  = blockIdx.x;
    // XCD-chunked swizzle: 784 = 8*98; the 4 n-groups of a panel share an XCD
    const int wid = (bid & 7) * 98 + (bid >> 3);
    const int tg  = wid >> 2, ng = wid & 3;
    const int t0  = tg << 7;
    const int n0g = ng << 7;

    if (tid < 128) {
        int t = t0 + tid;
        int nimg = t / 784, rem = t - nimg * 784;
        int h = rem / 28, w = rem - h * 28;
        s_pbase[tid] = nimg * 215296 + (2 * h) * 58 + 2 * w;   // xp elems
        s_obase[tid] = nimg * 401408 + (2 * h) * 56 + 2 * w;   // out elems
    }
    __syncthreads();

    // A-gather: thread -> (tile t, chalf); lane-consecutive tiles (coalesced)
    const int t     = tid & 127;
    const int chalf = tid >> 7;
    const int ebase0 = s_pbase[t] + chalf * 6728;

    int wbyte[4];
    #pragma unroll
    for (int q = 0; q < 4; ++q)
        wbyte[q] = (t * 128 + chalf * 64 + q * 16) ^ ((t & 7) << 4);

    const int fswz = (l15 & 7) << 4;
    int abase[4];
    #pragma unroll
    for (int fm = 0; fm < 4; ++fm)
        abase[fm] = (wm * 64 + fm * 16 + l15) * 128 + g * 16;

    // B: direct-from-global fragment addresses (n-major rows of 2048 B)
    const char* bb = (const char*)weff;
    unsigned int boff[4];
    #pragma unroll
    for (int fn = 0; fn < 4; ++fn)
        boff[fn] = (unsigned)((n0g + wn * 64 + fn * 16 + l15) * 2048 + g * 16);

    f32x4 acc[4][4];
    #pragma unroll
    for (int i = 0; i < 4; ++i)
        #pragma unroll
        for (int j = 0; j < 4; ++j)
            acc[i][j] = (f32x4){0.f, 0.f, 0.f, 0.f};

    unsigned int Ar[16];
    bf16x8 bg[8];

    auto GATHER_A = [&](int k) {
        const unsigned short* p = xp + (ebase0 + k * 13456);
        #pragma unroll
        for (int cp = 0; cp < 2; ++cp)
            #pragma unroll
            for (int b = 0; b < 4; ++b) {
                const unsigned short* q = p + cp * 3364 + b * 58;
                Ar[cp * 8 + b * 2]     = *(const unsigned int*)(q);
                Ar[cp * 8 + b * 2 + 1] = *(const unsigned int*)(q + 2);
            }
    };
    auto STAGE_A = [&](int buf) {
        #pragma unroll
        for (int q = 0; q < 4; ++q) {
            u32x4 v = {Ar[q * 4], Ar[q * 4 + 1], Ar[q * 4 + 2], Ar[q * 4 + 3]};
            *(u32x4*)(Abuf[buf] + wbyte[q]) = v;
        }
    };
    auto LOAD_B = [&](int k) {
        const char* q = bb + (unsigned)k * 128u;
        #pragma unroll
        for (int fn = 0; fn < 4; ++fn)
            #pragma unroll
            for (int ks = 0; ks < 2; ++ks)
                bg[fn * 2 + ks] = *(const bf16x8*)(q + boff[fn] + ks * 64);
    };
    auto MFMA_STEP = [&](int buf) {
        const unsigned char* Ab = Abuf[buf];
        __builtin_amdgcn_s_setprio(1);
        #pragma unroll
        for (int ks = 0; ks < 2; ++ks) {
            bf16x8 af[4];
            #pragma unroll
            for (int fm = 0; fm < 4; ++fm)
                af[fm] = *(const bf16x8*)(Ab + ((abase[fm] | (ks << 6)) ^ fswz));
            #pragma unroll
            for (int fm = 0; fm < 4; ++fm)
                #pragma unroll
                for (int fn = 0; fn < 4; ++fn)
                    acc[fm][fn] = __builtin_amdgcn_mfma_f32_16x16x32_bf16(
                        af[fm], bg[fn * 2 + ks], acc[fm][fn], 0, 0, 0);
        }
        __builtin_amdgcn_s_setprio(0);
    };

    // prologue: A(0) -> LDS buf0
    GATHER_A(0);
    STAGE_A(0);
    asm volatile("s_waitcnt lgkmcnt(0)" ::: "memory");
    __builtin_amdgcn_s_barrier();
    __builtin_amdgcn_sched_barrier(0);

    // step K: load B(K) regs; prefetch A(K+1) regs; MFMA buf K&1;
    // stage A(K+1) -> buf (K+1)&1; lgkm-only barrier (no vmcnt drain ever).
#define STEP(K, LAST)                                                       \
    do {                                                                    \
        LOAD_B(K);                                                          \
        if (!(LAST)) GATHER_A((K) + 1);                                     \
        MFMA_STEP((K) & 1);                                                 \
        if (!(LAST)) {                                                      \
            STAGE_A(((K) + 1) & 1);                                         \
            asm volatile("s_waitcnt lgkmcnt(0)" ::: "memory");              \
            __builtin_amdgcn_s_barrier();                                   \
            __builtin_amdgcn_sched_barrier(0);                              \
        }                                                                   \
    } while (0)

    STEP(0, 0);  STEP(1, 0);  STEP(2, 0);  STEP(3, 0);
    STEP(4, 0);  STEP(5, 0);  STEP(6, 0);  STEP(7, 0);
    STEP(8, 0);  STEP(9, 0);  STEP(10, 0); STEP(11, 0);
    STEP(12, 0); STEP(13, 0); STEP(14, 0); STEP(15, 1);
#undef STEP

    // ---- epilogue: per-wave LDS transpose -> contiguous float2 stores ----
    // bias fragments (per fn, lane's n-column)
    float bfn[4];
    #pragma unroll
    for (int fn = 0; fn < 4; ++fn)
        bfn[fn] = bias[(n0g + wn * 64 + fn * 16 + l15) >> 2];
    const int ob = s_obase[wm * 64 + lane];   // per-lane tile base (lane = m)

    asm volatile("s_waitcnt lgkmcnt(0)" ::: "memory");
    __builtin_amdgcn_s_barrier();             // all waves done reading Abuf
    __builtin_amdgcn_sched_barrier(0);

    float* esc = (float*)(&Abuf[0][0]) + wv * (64 * 17);   // 4.25KB/wave

    #pragma unroll
    for (int fn = 0; fn < 4; ++fn) {
        #pragma unroll
        for (int fm = 0; fm < 4; ++fm)
            #pragma unroll
            for (int r = 0; r < 4; ++r)
                esc[(fm * 16 + g * 4 + r) * 17 + l15] = acc[fm][fn][r] + bfn[fn];
        asm volatile("s_waitcnt lgkmcnt(0)" ::: "memory");
        __builtin_amdgcn_sched_barrier(0);
        const int ncb = n0g + wn * 64 + fn * 16;
        #pragma unroll
        for (int jp = 0; jp < 8; ++jp) {
            float v0 = esc[lane * 17 + 2 * jp];
            float v1 = esc[lane * 17 + 2 * jp + 1];
            int n = ncb + 2 * jp;
            int o = n >> 2, P = (n >> 1) & 1;
            f32x2 st = {v0, v1};
            *(f32x2*)(out + ob + o * 3136 + P * 56) = st;
        }
        asm volatile("s_waitcnt lgkmcnt(0)" ::: "memory");
        __builtin_amdgcn_sched_barrier(0);
    }
}

extern "C" void kernel_launch(void* const* d_in, const int* in_sizes, int n_in,
                              void* d_out, int out_size, void* d_ws, size_t ws_size,
                              hipStream_t stream)
{
    const float* x = (const float*)d_in[0];
    const float* w = (const float*)d_in[1];
    const float* b = (const float*)d_in[2];
    float* out = (float*)d_out;
    unsigned char* ws = (unsigned char*)d_ws;

    hipLaunchKernelGGL(prep, dim3(2048 + 32), dim3(256), 0, stream, x, w, ws);
    hipLaunchKernelGGL(conv_gemm, dim3(784), dim3(256), 0, stream,
                       (const unsigned short*)ws,
                       (const unsigned short*)(ws + BSTG_OFF), b, out);
}

// Round 10
// 93.002 us; speedup vs baseline: 1.0043x; 1.0043x over previous
//
#include <hip/hip_runtime.h>

typedef __attribute__((ext_vector_type(8))) short bf16x8;
typedef __attribute__((ext_vector_type(4))) float f32x4;
typedef __attribute__((ext_vector_type(2))) float f32x2;
typedef __attribute__((ext_vector_type(4))) unsigned int u32x4;

#define XP_BYTES (2048 * 3364 * 2)   // padded x, bf16: 32*64 planes of 58x58
#define BSTG_OFF XP_BYTES            // Weff: 512 x 1024 bf16, n-major (1 MB)

static __device__ __forceinline__ unsigned short f2bf(float v) {
    unsigned int u = __builtin_bit_cast(unsigned int, v);
    u += 0x7fffu + ((u >> 16) & 1u);
    return (unsigned short)(u >> 16);
}

// ---------------------------------------------------------------------------
// Prep: (a) pad+convert x to bf16 58x58 planes; (b) fold Hadamard transforms
// into direct-conv weights, n-major: weff[n'*1024 + c*16 + b*4 + a].
// ---------------------------------------------------------------------------
__global__ __launch_bounds__(256) void prep(const float* __restrict__ x,
                                            const float* __restrict__ w,
                                            unsigned char* __restrict__ ws)
{
    int bid = blockIdx.x;
    if (bid < 2048) {
        const float* src = x + (size_t)bid * 3136;
        unsigned int* dst = (unsigned int*)ws + (size_t)bid * 1682;
        for (int s = threadIdx.x; s < 1682; s += 256) {
            int r = s / 29, p = s - r * 29;
            float v0 = 0.f, v1 = 0.f;
            if (r >= 1 && r <= 56) {
                const float* row = src + (r - 1) * 56;
                if (p >= 1)  v0 = row[2 * p - 1];
                if (p <= 27) v1 = row[2 * p];
            }
            dst[s] = (unsigned int)f2bf(v0) | ((unsigned int)f2bf(v1) << 16);
        }
        return;
    }
    int idx = (bid - 2048) * 256 + threadIdx.x;   // (o,c) pair
    if (idx >= 128 * 64) return;
    int o = idx >> 6, c = idx & 63;
    const bool v2 = (o >= 64);
    const float Hm[4][4]  = {{1,1,1,1},{1,-1,1,-1},{1,1,-1,-1},{1,-1,-1,1}};
    const float H2m[4][4] = {{1,-1,1,-1},{1,1,1,1},{1,1,-1,-1},{1,-1,-1,1}};

    float wv[4][4];
    #pragma unroll
    for (int i = 0; i < 4; ++i)
        #pragma unroll
        for (int j = 0; j < 4; ++j)
            wv[i][j] = w[((o * 64 + c) * 4 + i) * 4 + j];

    float FA[4][4], FB[4][4], G[2][4];
    #pragma unroll
    for (int a = 0; a < 4; ++a)
        #pragma unroll
        for (int i = 0; i < 4; ++i) {
            FA[a][i] = v2 ? H2m[a][i] : Hm[i][a];
            FB[a][i] = v2 ? H2m[a][i] : Hm[a][i];
        }
    #pragma unroll
    for (int p = 0; p < 2; ++p)
        #pragma unroll
        for (int i = 0; i < 4; ++i)
            G[p][i] = 0.25f * (v2 ? H2m[p + 1][i] : Hm[p + 1][i]);

    unsigned short* weff = (unsigned short*)(ws + BSTG_OFF);
    #pragma unroll
    for (int P = 0; P < 2; ++P)
    #pragma unroll
    for (int Q = 0; Q < 2; ++Q) {
        int nrow = o * 4 + P * 2 + Q;
        #pragma unroll
        for (int b = 0; b < 4; ++b)
        #pragma unroll
        for (int a = 0; a < 4; ++a) {
            float s = 0.f;
            #pragma unroll
            for (int i = 0; i < 4; ++i) {
                float sj = 0.f;
                #pragma unroll
                for (int j = 0; j < 4; ++j)
                    sj += FB[b][j] * G[Q][j] * wv[i][j];
                s += G[P][i] * FA[a][i] * sj;
            }
            weff[(size_t)nrow * 1024 + c * 16 + b * 4 + a] = f2bf(s);
        }
    }
}

// ---------------------------------------------------------------------------
// Main GEMM. M=25088 (196x128), N=512 (4x128), K=1024 (16 steps x 64).
// 256 thr = 4 waves (2m x 2n); wave = 64m x 64n, 32 MFMA(16x16x32)/step.
// A: coalesced gather -> regs -> XOR-swizzled LDS (barrier'd, lgkm only).
// B: direct global -> per-wave regs (no LDS, no barrier dependency).
// LDS 33.8KB -> 3 blocks/CU (12 waves): TLP hides L2 latency across blocks.
// Epilogue: per-wave LDS transpose -> contiguous float2 stores.
// ---------------------------------------------------------------------------
__global__ __launch_bounds__(256, 3) void conv_gemm(
    const unsigned short* __restrict__ xp,
    const unsigned short* __restrict__ weff,
    const float* __restrict__ bias,
    float* __restrict__ out)
{
    __shared__ __align__(16) unsigned char Abuf[2][16384];
    __shared__ int s_pbase[128];
    __shared__ int s_obase[128];

    const int tid  = threadIdx.x;
    const int lane = tid & 63;
    const int l15  = lane & 15;
    const int g    = lane >> 4;
    const int wv   = tid >> 6;
    const int wm   = wv >> 1, wn = wv & 1;
    const int bid  = blockIdx.x;
    // XCD-chunked swizzle: 784 = 8*98; the 4 n-groups of a panel share an XCD
    const int wid = (bid & 7) * 98 + (bid >> 3);
    const int tg  = wid >> 2, ng = wid & 3;
    const int t0  = tg << 7;
    const int n0g = ng << 7;

    if (tid < 128) {
        int t = t0 + tid;
        int nimg = t / 784, rem = t - nimg * 784;
        int h = rem / 28, w = rem - h * 28;
        s_pbase[tid] = nimg * 215296 + (2 * h) * 58 + 2 * w;   // xp elems
        s_obase[tid] = nimg * 401408 + (2 * h) * 56 + 2 * w;   // out elems
    }
    __syncthreads();

    // A-gather: thread -> (tile t, chalf); lane-consecutive tiles (coalesced)
    const int t     = tid & 127;
    const int chalf = tid >> 7;
    const int ebase0 = s_pbase[t] + chalf * 6728;

    int wbyte[4];
    #pragma unroll
    for (int q = 0; q < 4; ++q)
        wbyte[q] = (t * 128 + chalf * 64 + q * 16) ^ ((t & 7) << 4);

    const int fswz = (l15 & 7) << 4;
    int abase[4];
    #pragma unroll
    for (int fm = 0; fm < 4; ++fm)
        abase[fm] = (wm * 64 + fm * 16 + l15) * 128 + g * 16;

    // B: direct-from-global fragment addresses (n-major rows of 2048 B)
    const char* bb = (const char*)weff;
    unsigned int boff[4];
    #pragma unroll
    for (int fn = 0; fn < 4; ++fn)
        boff[fn] = (unsigned)((n0g + wn * 64 + fn * 16 + l15) * 2048 + g * 16);

    f32x4 acc[4][4];
    #pragma unroll
    for (int i = 0; i < 4; ++i)
        #pragma unroll
        for (int j = 0; j < 4; ++j)
            acc[i][j] = (f32x4){0.f, 0.f, 0.f, 0.f};

    unsigned int Ar[16];
    bf16x8 bg[8];

    auto GATHER_A = [&](int k) {
        const unsigned short* p = xp + (ebase0 + k * 13456);
        #pragma unroll
        for (int cp = 0; cp < 2; ++cp)
            #pragma unroll
            for (int b = 0; b < 4; ++b) {
                const unsigned short* q = p + cp * 3364 + b * 58;
                Ar[cp * 8 + b * 2]     = *(const unsigned int*)(q);
                Ar[cp * 8 + b * 2 + 1] = *(const unsigned int*)(q + 2);
            }
    };
    auto STAGE_A = [&](int buf) {
        #pragma unroll
        for (int q = 0; q < 4; ++q) {
            u32x4 v = {Ar[q * 4], Ar[q * 4 + 1], Ar[q * 4 + 2], Ar[q * 4 + 3]};
            *(u32x4*)(Abuf[buf] + wbyte[q]) = v;
        }
    };
    auto LOAD_B = [&](int k) {
        const char* q = bb + (unsigned)k * 128u;
        #pragma unroll
        for (int fn = 0; fn < 4; ++fn)
            #pragma unroll
            for (int ks = 0; ks < 2; ++ks)
                bg[fn * 2 + ks] = *(const bf16x8*)(q + boff[fn] + ks * 64);
    };
    auto MFMA_STEP = [&](int buf) {
        const unsigned char* Ab = Abuf[buf];
        __builtin_amdgcn_s_setprio(1);
        #pragma unroll
        for (int ks = 0; ks < 2; ++ks) {
            bf16x8 af[4];
            #pragma unroll
            for (int fm = 0; fm < 4; ++fm)
                af[fm] = *(const bf16x8*)(Ab + ((abase[fm] | (ks << 6)) ^ fswz));
            #pragma unroll
            for (int fm = 0; fm < 4; ++fm)
                #pragma unroll
                for (int fn = 0; fn < 4; ++fn)
                    acc[fm][fn] = __builtin_amdgcn_mfma_f32_16x16x32_bf16(
                        af[fm], bg[fn * 2 + ks], acc[fm][fn], 0, 0, 0);
        }
        __builtin_amdgcn_s_setprio(0);
    };

    // prologue: A(0) -> LDS buf0
    GATHER_A(0);
    STAGE_A(0);
    asm volatile("s_waitcnt lgkmcnt(0)" ::: "memory");
    __builtin_amdgcn_s_barrier();
    __builtin_amdgcn_sched_barrier(0);

    // step K: load B(K) regs; prefetch A(K+1) regs; MFMA buf K&1;
    // stage A(K+1) -> buf (K+1)&1; lgkm-only barrier (no vmcnt drain ever).
#define STEP(K, LAST)                                                       \
    do {                                                                    \
        LOAD_B(K);                                                          \
        if (!(LAST)) GATHER_A((K) + 1);                                     \
        MFMA_STEP((K) & 1);                                                 \
        if (!(LAST)) {                                                      \
            STAGE_A(((K) + 1) & 1);                                         \
            asm volatile("s_waitcnt lgkmcnt(0)" ::: "memory");              \
            __builtin_amdgcn_s_barrier();                                   \
            __builtin_amdgcn_sched_barrier(0);                              \
        }                                                                   \
    } while (0)

    STEP(0, 0);  STEP(1, 0);  STEP(2, 0);  STEP(3, 0);
    STEP(4, 0);  STEP(5, 0);  STEP(6, 0);  STEP(7, 0);
    STEP(8, 0);  STEP(9, 0);  STEP(10, 0); STEP(11, 0);
    STEP(12, 0); STEP(13, 0); STEP(14, 0); STEP(15, 1);
#undef STEP

    // ---- epilogue: per-wave LDS transpose -> contiguous float2 stores ----
    // bias fragments (per fn, lane's n-column)
    float bfn[4];
    #pragma unroll
    for (int fn = 0; fn < 4; ++fn)
        bfn[fn] = bias[(n0g + wn * 64 + fn * 16 + l15) >> 2];
    const int ob = s_obase[wm * 64 + lane];   // per-lane tile base (lane = m)

    asm volatile("s_waitcnt lgkmcnt(0)" ::: "memory");
    __builtin_amdgcn_s_barrier();             // all waves done reading Abuf
    __builtin_amdgcn_sched_barrier(0);

    float* esc = (float*)(&Abuf[0][0]) + wv * (64 * 17);   // 4.25KB/wave

    #pragma unroll
    for (int fn = 0; fn < 4; ++fn) {
        #pragma unroll
        for (int fm = 0; fm < 4; ++fm)
            #pragma unroll
            for (int r = 0; r < 4; ++r)
                esc[(fm * 16 + g * 4 + r) * 17 + l15] = acc[fm][fn][r] + bfn[fn];
        asm volatile("s_waitcnt lgkmcnt(0)" ::: "memory");
        __builtin_amdgcn_sched_barrier(0);
        const int ncb = n0g + wn * 64 + fn * 16;
        #pragma unroll
        for (int jp = 0; jp < 8; ++jp) {
            float v0 = esc[lane * 17 + 2 * jp];
            float v1 = esc[lane * 17 + 2 * jp + 1];
            int n = ncb + 2 * jp;
            int o = n >> 2, P = (n >> 1) & 1;
            f32x2 st = {v0, v1};
            *(f32x2*)(out + ob + o * 3136 + P * 56) = st;
        }
        asm volatile("s_waitcnt lgkmcnt(0)" ::: "memory");
        __builtin_amdgcn_sched_barrier(0);
    }
}

extern "C" void kernel_launch(void* const* d_in, const int* in_sizes, int n_in,
                              void* d_out, int out_size, void* d_ws, size_t ws_size,
                              hipStream_t stream)
{
    const float* x = (const float*)d_in[0];
    const float* w = (const float*)d_in[1];
    const float* b = (const float*)d_in[2];
    float* out = (float*)d_out;
    unsigned char* ws = (unsigned char*)d_ws;

    hipLaunchKernelGGL(prep, dim3(2048 + 32), dim3(256), 0, stream, x, w, ws);
    hipLaunchKernelGGL(conv_gemm, dim3(784), dim3(256), 0, stream,
                       (const unsigned short*)ws,
                       (const unsigned short*)(ws + BSTG_OFF), b, out);
}